// Round 1
// baseline (563.949 us; speedup 1.0000x reference)
//
#include <hip/hip_runtime.h>
#include <hip/hip_bf16.h>

typedef __attribute__((ext_vector_type(8))) short bf16x8;
typedef __attribute__((ext_vector_type(8))) unsigned short u16x8;
typedef __attribute__((ext_vector_type(4))) float f32x4;

#define MFMA16(a, b, c) __builtin_amdgcn_mfma_f32_16x16x32_bf16(a, b, c, 0, 0, 0)

__device__ __forceinline__ unsigned short f2bf(float x) {
    unsigned u = __builtin_bit_cast(unsigned, x);
    u += 0x7FFFu + ((u >> 16) & 1u);
    return (unsigned short)(u >> 16);
}

constexpr int NSEQ = 8192;
constexpr int NH   = 8;
constexpr int DIM  = 64;
constexpr int KVB  = 64;   // keys per LDS tile
constexpr int QB   = 128;  // q rows per block (4 waves x 32)
constexpr int LDK  = 72;   // padded LDS row stride (ushorts), 144B = 36 banks

__global__ __launch_bounds__(256, 2)
void fa_kernel(const float* __restrict__ Qg, const float* __restrict__ Kg,
               const float* __restrict__ Vg, float* __restrict__ Og) {
    __shared__ unsigned short Kl[KVB][LDK];      // [key][d] bf16
    __shared__ unsigned short Vt[DIM][LDK];      // [d][key] bf16 (transposed)
    __shared__ unsigned short Pl[4][32][LDK];    // per-wave P [qrow][key]

    const int tid   = threadIdx.x;
    const int lane  = tid & 63;
    const int wave  = tid >> 6;
    const int head  = blockIdx.x >> 6;   // 8 heads x 64 qtiles
    const int qtile = blockIdx.x & 63;
    const int qbase = qtile * QB + wave * 32;
    const int lr = lane & 15;   // position-in-16 (row for A, col for B/C)
    const int lk = lane >> 4;   // k-group 0..3

    // ---- Q fragments, x0.125 folded in (exact pow2) ----
    bf16x8 qf[2][2];
#pragma unroll
    for (int mt = 0; mt < 2; ++mt)
#pragma unroll
        for (int ks = 0; ks < 2; ++ks) {
            const float* src = Qg + ((size_t)(qbase + mt * 16 + lr) * NH + head) * DIM + ks * 32 + lk * 8;
            float4 a = ((const float4*)src)[0];
            float4 b = ((const float4*)src)[1];
            bf16x8 f;
            f[0] = (short)f2bf(a.x * 0.125f); f[1] = (short)f2bf(a.y * 0.125f);
            f[2] = (short)f2bf(a.z * 0.125f); f[3] = (short)f2bf(a.w * 0.125f);
            f[4] = (short)f2bf(b.x * 0.125f); f[5] = (short)f2bf(b.y * 0.125f);
            f[6] = (short)f2bf(b.z * 0.125f); f[7] = (short)f2bf(b.w * 0.125f);
            qf[mt][ks] = f;
        }

    // staging map: each thread loads one key-row quarter (64B), conflict-free LDS writes
    const int srow = tid & 63;          // key row within tile
    const int scol = (tid >> 6) * 16;   // d-column group

    float m_run[2][4], l_run[2][4];
    f32x4 o_acc[2][4];
#pragma unroll
    for (int mt = 0; mt < 2; ++mt)
#pragma unroll
        for (int r = 0; r < 4; ++r) { m_run[mt][r] = -1e30f; l_run[mt][r] = 0.f; }
#pragma unroll
    for (int mt = 0; mt < 2; ++mt)
#pragma unroll
        for (int nt = 0; nt < 4; ++nt) o_acc[mt][nt] = f32x4{0.f, 0.f, 0.f, 0.f};

    for (int kb = 0; kb < NSEQ; kb += KVB) {
        __syncthreads();  // previous tile's LDS reads done before overwrite
        // ---- stage K tile [key][d] as bf16 ----
        {
            const float* kp = Kg + ((size_t)(kb + srow) * NH + head) * DIM + scol;
            float4 a0 = ((const float4*)kp)[0], a1 = ((const float4*)kp)[1];
            float4 a2 = ((const float4*)kp)[2], a3 = ((const float4*)kp)[3];
            u16x8 w0, w1;
            w0[0] = f2bf(a0.x); w0[1] = f2bf(a0.y); w0[2] = f2bf(a0.z); w0[3] = f2bf(a0.w);
            w0[4] = f2bf(a1.x); w0[5] = f2bf(a1.y); w0[6] = f2bf(a1.z); w0[7] = f2bf(a1.w);
            w1[0] = f2bf(a2.x); w1[1] = f2bf(a2.y); w1[2] = f2bf(a2.z); w1[3] = f2bf(a2.w);
            w1[4] = f2bf(a3.x); w1[5] = f2bf(a3.y); w1[6] = f2bf(a3.z); w1[7] = f2bf(a3.w);
            *(u16x8*)&Kl[srow][scol]     = w0;
            *(u16x8*)&Kl[srow][scol + 8] = w1;

            // ---- stage V tile transposed [d][key] ----
            const float* vp = Vg + ((size_t)(kb + srow) * NH + head) * DIM + scol;
            float4 b0 = ((const float4*)vp)[0], b1 = ((const float4*)vp)[1];
            float4 b2 = ((const float4*)vp)[2], b3 = ((const float4*)vp)[3];
            Vt[scol + 0][srow]  = f2bf(b0.x); Vt[scol + 1][srow]  = f2bf(b0.y);
            Vt[scol + 2][srow]  = f2bf(b0.z); Vt[scol + 3][srow]  = f2bf(b0.w);
            Vt[scol + 4][srow]  = f2bf(b1.x); Vt[scol + 5][srow]  = f2bf(b1.y);
            Vt[scol + 6][srow]  = f2bf(b1.z); Vt[scol + 7][srow]  = f2bf(b1.w);
            Vt[scol + 8][srow]  = f2bf(b2.x); Vt[scol + 9][srow]  = f2bf(b2.y);
            Vt[scol + 10][srow] = f2bf(b2.z); Vt[scol + 11][srow] = f2bf(b2.w);
            Vt[scol + 12][srow] = f2bf(b3.x); Vt[scol + 13][srow] = f2bf(b3.y);
            Vt[scol + 14][srow] = f2bf(b3.z); Vt[scol + 15][srow] = f2bf(b3.w);
        }
        __syncthreads();

        // ---- S = (Q*scale) K^T : 16 MFMA per wave ----
        f32x4 s[2][4];
#pragma unroll
        for (int nt = 0; nt < 4; ++nt) {
            bf16x8 k0 = *(const bf16x8*)&Kl[nt * 16 + lr][lk * 8];
            bf16x8 k1 = *(const bf16x8*)&Kl[nt * 16 + lr][32 + lk * 8];
#pragma unroll
            for (int mt = 0; mt < 2; ++mt) {
                f32x4 acc = f32x4{0.f, 0.f, 0.f, 0.f};
                acc = MFMA16(qf[mt][0], k0, acc);
                acc = MFMA16(qf[mt][1], k1, acc);
                s[mt][nt] = acc;
            }
        }

        // ---- online softmax (C-layout: col=lr, row=lk*4+r) ----
#pragma unroll
        for (int mt = 0; mt < 2; ++mt) {
            float mx[4], corr[4], rs[4];
#pragma unroll
            for (int r = 0; r < 4; ++r)
                mx[r] = fmaxf(fmaxf(s[mt][0][r], s[mt][1][r]), fmaxf(s[mt][2][r], s[mt][3][r]));
#pragma unroll
            for (int msk = 1; msk <= 8; msk <<= 1)
#pragma unroll
                for (int r = 0; r < 4; ++r)
                    mx[r] = fmaxf(mx[r], __shfl_xor(mx[r], msk));
#pragma unroll
            for (int r = 0; r < 4; ++r) {
                float mnew = fmaxf(m_run[mt][r], mx[r]);
                corr[r] = __expf(m_run[mt][r] - mnew);
                m_run[mt][r] = mnew;
                l_run[mt][r] *= corr[r];
                rs[r] = 0.f;
            }
#pragma unroll
            for (int nt = 0; nt < 4; ++nt)
#pragma unroll
                for (int r = 0; r < 4; ++r) {
                    float p = __expf(s[mt][nt][r] - m_run[mt][r]);
                    s[mt][nt][r] = p;
                    rs[r] += p;
                }
#pragma unroll
            for (int msk = 1; msk <= 8; msk <<= 1)
#pragma unroll
                for (int r = 0; r < 4; ++r)
                    rs[r] += __shfl_xor(rs[r], msk);
#pragma unroll
            for (int r = 0; r < 4; ++r) l_run[mt][r] += rs[r];
#pragma unroll
            for (int nt = 0; nt < 4; ++nt)
#pragma unroll
                for (int r = 0; r < 4; ++r)
                    o_acc[mt][nt][r] *= corr[r];
            // P -> per-wave LDS (bf16), C-layout scatter
#pragma unroll
            for (int nt = 0; nt < 4; ++nt)
#pragma unroll
                for (int r = 0; r < 4; ++r)
                    Pl[wave][mt * 16 + lk * 4 + r][nt * 16 + lr] = f2bf(s[mt][nt][r]);
        }

        // ---- O += P V : 16 MFMA per wave ----
#pragma unroll
        for (int ks = 0; ks < 2; ++ks) {
            bf16x8 p0 = *(const bf16x8*)&Pl[wave][lr][ks * 32 + lk * 8];
            bf16x8 p1 = *(const bf16x8*)&Pl[wave][16 + lr][ks * 32 + lk * 8];
#pragma unroll
            for (int nt = 0; nt < 4; ++nt) {
                bf16x8 vf = *(const bf16x8*)&Vt[nt * 16 + lr][ks * 32 + lk * 8];
                o_acc[0][nt] = MFMA16(p0, vf, o_acc[0][nt]);
                o_acc[1][nt] = MFMA16(p1, vf, o_acc[1][nt]);
            }
        }
    }

    // ---- epilogue: O/l, fp32 out [n][h][d] ----
#pragma unroll
    for (int mt = 0; mt < 2; ++mt)
#pragma unroll
        for (int nt = 0; nt < 4; ++nt)
#pragma unroll
            for (int r = 0; r < 4; ++r) {
                float val = o_acc[mt][nt][r] / l_run[mt][r];
                Og[((size_t)(qbase + mt * 16 + lk * 4 + r) * NH + head) * DIM + nt * 16 + lr] = val;
            }
}

extern "C" void kernel_launch(void* const* d_in, const int* in_sizes, int n_in,
                              void* d_out, int out_size, void* d_ws, size_t ws_size,
                              hipStream_t stream) {
    const float* q = (const float*)d_in[0];
    const float* k = (const float*)d_in[1];
    const float* v = (const float*)d_in[2];
    float* out = (float*)d_out;
    dim3 grid(512), block(256);
    hipLaunchKernelGGL(fa_kernel, grid, block, 0, stream, q, k, v, out);
}

// Round 2
// 334.430 us; speedup vs baseline: 1.6863x; 1.6863x over previous
//
#include <hip/hip_runtime.h>
#include <hip/hip_bf16.h>

typedef __attribute__((ext_vector_type(8))) short bf16x8;
typedef __attribute__((ext_vector_type(4))) float f32x4;
typedef __attribute__((ext_vector_type(4))) unsigned int u32x4;

#define MFMA16(a, b, c) __builtin_amdgcn_mfma_f32_16x16x32_bf16(a, b, c, 0, 0, 0)

constexpr int NSEQ = 8192;
constexpr int NH   = 8;
constexpr int DIM  = 64;
constexpr int KVB  = 64;    // keys per LDS tile
constexpr int QB   = 128;   // q rows per block (8 waves x 16)
constexpr int LDK  = 72;    // padded LDS row stride (ushorts)
constexpr float SCL2 = 0.18033688011112042f;  // 0.125 * log2(e): scores in log2 domain

__device__ __forceinline__ unsigned cvt_pk(float lo, float hi) {
    unsigned r;
    asm("v_cvt_pk_bf16_f32 %0, %1, %2" : "=v"(r) : "v"(lo), "v"(hi));
    return r;
}
__device__ __forceinline__ float exp2f_fast(float x) {
    float r;
    asm("v_exp_f32 %0, %1" : "=v"(r) : "v"(x));
    return r;
}
template <int CTRL>
__device__ __forceinline__ float row_ror(float x) {
    int i = __builtin_bit_cast(int, x);
    i = __builtin_amdgcn_mov_dpp(i, CTRL, 0xF, 0xF, true);
    return __builtin_bit_cast(float, i);
}

__global__ __launch_bounds__(512, 4)
void fa_kernel(const float* __restrict__ Qg, const float* __restrict__ Kg,
               const float* __restrict__ Vg, float* __restrict__ Og) {
    __shared__ unsigned short Kl[KVB][LDK];    // [key][d] bf16
    __shared__ unsigned short Vt[DIM][LDK];    // [d][key] bf16 (transposed)
    __shared__ unsigned short Pl[8][16][LDK];  // per-wave P [qrow][key], col-swizzled

    const int tid  = threadIdx.x;
    const int lane = tid & 63;
    const int wave = tid >> 6;
    const int head  = blockIdx.x >> 6;
    const int qtile = blockIdx.x & 63;
    const int qbase = qtile * QB + wave * 16;
    const int lr = lane & 15;
    const int lk = lane >> 4;

    // ---- Q fragments, scale folded (log2 domain) ----
    bf16x8 qf[2];
    {
        const float* qp = Qg + ((size_t)(qbase + lr) * NH + head) * DIM + lk * 8;
#pragma unroll
        for (int ks = 0; ks < 2; ++ks) {
            float4 a = ((const float4*)(qp + ks * 32))[0];
            float4 b = ((const float4*)(qp + ks * 32))[1];
            u32x4 w;
            w[0] = cvt_pk(a.x * SCL2, a.y * SCL2);
            w[1] = cvt_pk(a.z * SCL2, a.w * SCL2);
            w[2] = cvt_pk(b.x * SCL2, b.y * SCL2);
            w[3] = cvt_pk(b.z * SCL2, b.w * SCL2);
            qf[ks] = __builtin_bit_cast(bf16x8, w);
        }
    }

    // staging map: srow = key row (lane), scol = 8-float column slice (per wave)
    const int srow = lane;
    const int scol = wave * 8;
    const float* kp = Kg + ((size_t)srow * NH + head) * DIM + scol;
    const float* vp = Vg + ((size_t)srow * NH + head) * DIM + scol;
    constexpr size_t TILE_STRIDE = (size_t)KVB * NH * DIM;

    float m_run[4], l_run[4];
    f32x4 o_acc[4];
#pragma unroll
    for (int r = 0; r < 4; ++r) { m_run[r] = -1e30f; l_run[r] = 0.f; }
#pragma unroll
    for (int nt = 0; nt < 4; ++nt) o_acc[nt] = f32x4{0.f, 0.f, 0.f, 0.f};

    // prefetch tile 0
    float4 ka0 = ((const float4*)kp)[0], ka1 = ((const float4*)kp)[1];
    float4 va0 = ((const float4*)vp)[0], va1 = ((const float4*)vp)[1];
    kp += TILE_STRIDE; vp += TILE_STRIDE;

    for (int kb = 0; kb < NSEQ; kb += KVB) {
        __syncthreads();  // readers of previous tile done
        // ---- stage K (b128) ----
        {
            u32x4 w;
            w[0] = cvt_pk(ka0.x, ka0.y); w[1] = cvt_pk(ka0.z, ka0.w);
            w[2] = cvt_pk(ka1.x, ka1.y); w[3] = cvt_pk(ka1.z, ka1.w);
            *(u32x4*)&Kl[srow][scol] = w;
        }
        // ---- stage V transposed (scalar b16, stride-2B lanes: conflict-free) ----
        {
            unsigned u;
            u = cvt_pk(va0.x, va0.y); Vt[scol + 0][srow] = (unsigned short)u; Vt[scol + 1][srow] = (unsigned short)(u >> 16);
            u = cvt_pk(va0.z, va0.w); Vt[scol + 2][srow] = (unsigned short)u; Vt[scol + 3][srow] = (unsigned short)(u >> 16);
            u = cvt_pk(va1.x, va1.y); Vt[scol + 4][srow] = (unsigned short)u; Vt[scol + 5][srow] = (unsigned short)(u >> 16);
            u = cvt_pk(va1.z, va1.w); Vt[scol + 6][srow] = (unsigned short)u; Vt[scol + 7][srow] = (unsigned short)(u >> 16);
        }
        // ---- prefetch next tile (T14: latency hides under compute) ----
        if (kb + KVB < NSEQ) {
            ka0 = ((const float4*)kp)[0]; ka1 = ((const float4*)kp)[1];
            va0 = ((const float4*)vp)[0]; va1 = ((const float4*)vp)[1];
            kp += TILE_STRIDE; vp += TILE_STRIDE;
        }
        __syncthreads();

        // ---- S = QK^T (log2 domain): 8 MFMA ----
        f32x4 s[4];
#pragma unroll
        for (int nt = 0; nt < 4; ++nt) {
            bf16x8 k0 = *(const bf16x8*)&Kl[nt * 16 + lr][lk * 8];
            bf16x8 k1 = *(const bf16x8*)&Kl[nt * 16 + lr][32 + lk * 8];
            f32x4 acc = f32x4{0.f, 0.f, 0.f, 0.f};
            acc = MFMA16(qf[0], k0, acc);
            acc = MFMA16(qf[1], k1, acc);
            s[nt] = acc;
        }

        // ---- online softmax, defer-max THR=8 (T13) ----
        float pmax[4];
#pragma unroll
        for (int r = 0; r < 4; ++r)
            pmax[r] = fmaxf(fmaxf(s[0][r], s[1][r]), fmaxf(s[2][r], s[3][r]));
        bool ok = (pmax[0] <= m_run[0] + 8.f) && (pmax[1] <= m_run[1] + 8.f) &&
                  (pmax[2] <= m_run[2] + 8.f) && (pmax[3] <= m_run[3] + 8.f);
        if (!__all(ok)) {
#pragma unroll
            for (int r = 0; r < 4; ++r) {
                float mx = pmax[r];
                mx = fmaxf(mx, row_ror<0x128>(mx));
                mx = fmaxf(mx, row_ror<0x124>(mx));
                mx = fmaxf(mx, row_ror<0x122>(mx));
                mx = fmaxf(mx, row_ror<0x121>(mx));
                float mnew = fmaxf(m_run[r], mx);
                float corr = exp2f_fast(m_run[r] - mnew);
                m_run[r] = mnew;
                l_run[r] *= corr;
#pragma unroll
                for (int nt = 0; nt < 4; ++nt) o_acc[nt][r] *= corr;
            }
        }
#pragma unroll
        for (int nt = 0; nt < 4; ++nt)
#pragma unroll
            for (int r = 0; r < 4; ++r) {
                float p = exp2f_fast(s[nt][r] - m_run[r]);
                s[nt][r] = p;
                l_run[r] += p;  // per-lane partial; reduced in epilogue
            }

        // ---- P -> LDS bf16, XOR-swizzled cols (conflict-free write & read) ----
#pragma unroll
        for (int nt = 0; nt < 4; ++nt) {
            const int col = (nt * 16 + lr) ^ (lk << 3);
            unsigned u01 = cvt_pk(s[nt][0], s[nt][1]);
            unsigned u23 = cvt_pk(s[nt][2], s[nt][3]);
            Pl[wave][lk * 4 + 0][col] = (unsigned short)u01;
            Pl[wave][lk * 4 + 1][col] = (unsigned short)(u01 >> 16);
            Pl[wave][lk * 4 + 2][col] = (unsigned short)u23;
            Pl[wave][lk * 4 + 3][col] = (unsigned short)(u23 >> 16);
        }

        // ---- O += P V : 8 MFMA ----
#pragma unroll
        for (int ks = 0; ks < 2; ++ks) {
            bf16x8 pa = *(const bf16x8*)&Pl[wave][lr][(ks * 32 + lk * 8) ^ ((lr & 12) << 1)];
#pragma unroll
            for (int nt = 0; nt < 4; ++nt) {
                bf16x8 vf = *(const bf16x8*)&Vt[nt * 16 + lr][ks * 32 + lk * 8];
                o_acc[nt] = MFMA16(pa, vf, o_acc[nt]);
            }
        }
    }

    // ---- epilogue: reduce l across lr lanes, divide, store ----
    float inv[4];
#pragma unroll
    for (int r = 0; r < 4; ++r) {
        float l = l_run[r];
        l += row_ror<0x128>(l);
        l += row_ror<0x124>(l);
        l += row_ror<0x122>(l);
        l += row_ror<0x121>(l);
        inv[r] = __builtin_amdgcn_rcpf(l);
    }
#pragma unroll
    for (int nt = 0; nt < 4; ++nt)
#pragma unroll
        for (int r = 0; r < 4; ++r)
            Og[((size_t)(qbase + lk * 4 + r) * NH + head) * DIM + nt * 16 + lr] =
                o_acc[nt][r] * inv[r];
}

extern "C" void kernel_launch(void* const* d_in, const int* in_sizes, int n_in,
                              void* d_out, int out_size, void* d_ws, size_t ws_size,
                              hipStream_t stream) {
    const float* q = (const float*)d_in[0];
    const float* k = (const float*)d_in[1];
    const float* v = (const float*)d_in[2];
    float* out = (float*)d_out;
    dim3 grid(512), block(512);
    hipLaunchKernelGGL(fa_kernel, grid, block, 0, stream, q, k, v, out);
}

// Round 4
// 238.665 us; speedup vs baseline: 2.3629x; 1.4013x over previous
//
#include <hip/hip_runtime.h>
#include <hip/hip_bf16.h>

typedef __attribute__((ext_vector_type(8))) short bf16x8;
typedef __attribute__((ext_vector_type(16))) float f32x16;
typedef __attribute__((ext_vector_type(4))) unsigned int u32x4;

#define MFMA32(a, b, c) __builtin_amdgcn_mfma_f32_32x32x16_bf16(a, b, c, 0, 0, 0)

constexpr int NSEQ = 8192;
constexpr int NH   = 8;
constexpr int DIM  = 64;
constexpr int KVB  = 64;
constexpr int QB   = 128;   // 4 waves x 32 q-rows
constexpr float SCL2 = 0.18033688011112042f;  // 0.125 * log2(e)

__device__ __forceinline__ unsigned cvt_pk(float lo, float hi) {
    unsigned r;
    asm("v_cvt_pk_bf16_f32 %0, %1, %2" : "=v"(r) : "v"(lo), "v"(hi));
    return r;
}
__device__ __forceinline__ float exp2f_fast(float x) {
    float r;
    asm("v_exp_f32 %0, %1" : "=v"(r) : "v"(x));
    return r;
}
// safe ONLY with provably-distinct operands (distinct live values)
__device__ __forceinline__ void pl32swap(unsigned& a, unsigned& b) {
    asm("v_permlane32_swap_b32 %0, %1" : "+v"(a), "+v"(b));
}
// XOR-swizzled LDS index (ushort units) for [row][64] bf16 tiles, 16B chunks
__device__ __forceinline__ int swz(int row, int col) {
    return row * 64 + ((((col >> 3) ^ row) & 7) << 3) + (col & 7);
}

__global__ __launch_bounds__(256, 2)
void fa_kernel(const float* __restrict__ Qg, const float* __restrict__ Kg,
               const float* __restrict__ Vg, float* __restrict__ Og) {
    __shared__ unsigned short Kl[KVB][DIM];   // [key][d] bf16, chunk-swizzled
    __shared__ unsigned short Vt[DIM][KVB];   // [d][key] bf16, chunk-swizzled

    unsigned short* Kbase = &Kl[0][0];
    unsigned short* Vbase = &Vt[0][0];

    const int tid  = threadIdx.x;
    const int lane = tid & 63;
    const int wave = tid >> 6;
    const int la31 = lane & 31;
    const int hi   = lane >> 5;
    const int head  = blockIdx.x & 7;    // head pinned per XCD
    const int qtile = blockIdx.x >> 3;
    const int q     = qtile * QB + wave * 32 + la31;  // this lane's q-row

    // ---- persistent Q B-fragments: qf[kd] = Q[q][16kd + 8hi + 0..7] * SCL2 ----
    bf16x8 qf[4];
#pragma unroll
    for (int kd = 0; kd < 4; ++kd) {
        const float* qp = Qg + ((size_t)q * NH + head) * DIM + kd * 16 + hi * 8;
        float4 a = ((const float4*)qp)[0];
        float4 b = ((const float4*)qp)[1];
        u32x4 w;
        w[0] = cvt_pk(a.x * SCL2, a.y * SCL2);
        w[1] = cvt_pk(a.z * SCL2, a.w * SCL2);
        w[2] = cvt_pk(b.x * SCL2, b.y * SCL2);
        w[3] = cvt_pk(b.z * SCL2, b.w * SCL2);
        qf[kd] = __builtin_bit_cast(bf16x8, w);
    }

    // ---- staging maps ----
    const int ksrow = tid & 63;          // key row
    const int kscol = (tid >> 6) * 16;   // 16 d-columns per wave
    const int vpair = tid & 31;          // key pair
    const int vcg   = tid >> 5;          // d-column group (0..7)
    const float* kptr  = Kg + ((size_t)ksrow * NH + head) * DIM + kscol;
    const float* vptr0 = Vg + ((size_t)(2 * vpair) * NH + head) * DIM + vcg * 8;
    const float* vptr1 = vptr0 + NH * DIM;
    constexpr size_t STRIDE = (size_t)KVB * NH * DIM;

    const int kIdx0 = swz(ksrow, kscol);
    const int kIdx1 = swz(ksrow, kscol + 8);

    f32x16 oacc[2];
#pragma unroll
    for (int nt = 0; nt < 2; ++nt)
#pragma unroll
        for (int i = 0; i < 16; ++i) oacc[nt][i] = 0.f;
    float m_run = -1e30f, l_run = 0.f;

    // prologue: prefetch tile 0
    float4 kr0 = ((const float4*)kptr)[0], kr1 = ((const float4*)kptr)[1];
    float4 kr2 = ((const float4*)kptr)[2], kr3 = ((const float4*)kptr)[3];
    float4 va0 = ((const float4*)vptr0)[0], va1 = ((const float4*)vptr0)[1];
    float4 vb0 = ((const float4*)vptr1)[0], vb1 = ((const float4*)vptr1)[1];
    kptr += STRIDE; vptr0 += STRIDE; vptr1 += STRIDE;

    constexpr int NT = NSEQ / KVB;
    for (int t = 0; t < NT; ++t) {
        __syncthreads();  // previous tile's readers done
        // ---- stage K (2 x b128, swizzled) ----
        {
            u32x4 w;
            w[0] = cvt_pk(kr0.x, kr0.y); w[1] = cvt_pk(kr0.z, kr0.w);
            w[2] = cvt_pk(kr1.x, kr1.y); w[3] = cvt_pk(kr1.z, kr1.w);
            *(u32x4*)(Kbase + kIdx0) = w;
            w[0] = cvt_pk(kr2.x, kr2.y); w[1] = cvt_pk(kr2.z, kr2.w);
            w[2] = cvt_pk(kr3.x, kr3.y); w[3] = cvt_pk(kr3.z, kr3.w);
            *(u32x4*)(Kbase + kIdx1) = w;
        }
        // ---- stage V transposed, pair-packed b32 writes (swizzled) ----
        {
            *(unsigned*)(Vbase + swz(vcg * 8 + 0, 2 * vpair)) = cvt_pk(va0.x, vb0.x);
            *(unsigned*)(Vbase + swz(vcg * 8 + 1, 2 * vpair)) = cvt_pk(va0.y, vb0.y);
            *(unsigned*)(Vbase + swz(vcg * 8 + 2, 2 * vpair)) = cvt_pk(va0.z, vb0.z);
            *(unsigned*)(Vbase + swz(vcg * 8 + 3, 2 * vpair)) = cvt_pk(va0.w, vb0.w);
            *(unsigned*)(Vbase + swz(vcg * 8 + 4, 2 * vpair)) = cvt_pk(va1.x, vb1.x);
            *(unsigned*)(Vbase + swz(vcg * 8 + 5, 2 * vpair)) = cvt_pk(va1.y, vb1.y);
            *(unsigned*)(Vbase + swz(vcg * 8 + 6, 2 * vpair)) = cvt_pk(va1.z, vb1.z);
            *(unsigned*)(Vbase + swz(vcg * 8 + 7, 2 * vpair)) = cvt_pk(va1.w, vb1.w);
        }
        __syncthreads();
        // ---- T14: issue next tile's loads; latency hides under compute ----
        if (t + 1 < NT) {
            kr0 = ((const float4*)kptr)[0]; kr1 = ((const float4*)kptr)[1];
            kr2 = ((const float4*)kptr)[2]; kr3 = ((const float4*)kptr)[3];
            va0 = ((const float4*)vptr0)[0]; va1 = ((const float4*)vptr0)[1];
            vb0 = ((const float4*)vptr1)[0]; vb1 = ((const float4*)vptr1)[1];
            kptr += STRIDE; vptr0 += STRIDE; vptr1 += STRIDE;
        }

        // ---- S^T = K (Q*scale)^T : 8 MFMA 32x32x16 ----
        f32x16 s0, s1;
#pragma unroll
        for (int i = 0; i < 16; ++i) { s0[i] = 0.f; s1[i] = 0.f; }
        __builtin_amdgcn_s_setprio(1);
#pragma unroll
        for (int kd = 0; kd < 4; ++kd) {
            bf16x8 k0 = *(const bf16x8*)(Kbase + swz(la31, kd * 16 + hi * 8));
            bf16x8 k1 = *(const bf16x8*)(Kbase + swz(32 + la31, kd * 16 + hi * 8));
            s0 = MFMA32(k0, qf[kd], s0);
            s1 = MFMA32(k1, qf[kd], s1);
        }
        __builtin_amdgcn_s_setprio(0);

        // ---- lane-local max over 32 scores, then pair-combine via shfl ----
        float pmv[16];
#pragma unroll
        for (int i = 0; i < 16; ++i) pmv[i] = fmaxf(s0[i], s1[i]);
#pragma unroll
        for (int st = 8; st >= 1; st >>= 1)
#pragma unroll
            for (int i = 0; i < 8; ++i)
                if (i < st) pmv[i] = fmaxf(pmv[i], pmv[i + st]);
        float pm = pmv[0];
        pm = fmaxf(pm, __shfl_xor(pm, 32));  // pair lanes share a q-row

        // ---- defer-max (T13, THR=8 in log2 domain) ----
        if (__any(pm > m_run + 8.f)) {
            float mnew = fmaxf(m_run, pm);
            float corr = exp2f_fast(m_run - mnew);
            m_run = mnew;
            l_run *= corr;
#pragma unroll
            for (int i = 0; i < 16; ++i) { oacc[0][i] *= corr; oacc[1][i] *= corr; }
        }

        // ---- per key-block: exp, pack P in-register (T12), PV MFMAs ----
#pragma unroll
        for (int kb = 0; kb < 2; ++kb) {
            const f32x16& s = kb ? s1 : s0;
            float p[16];
#pragma unroll
            for (int i = 0; i < 16; ++i) p[i] = exp2f_fast(s[i] - m_run);
            // l partial (tree)
            float ts[8];
#pragma unroll
            for (int i = 0; i < 8; ++i) ts[i] = p[i] + p[i + 8];
#pragma unroll
            for (int i = 0; i < 4; ++i) ts[i] += ts[i + 4];
            l_run += (ts[0] + ts[1]) + (ts[2] + ts[3]);
            // cvt_pk + permlane32_swap -> PV B-fragments (P^T rows)
            unsigned A[8];
#pragma unroll
            for (int j = 0; j < 8; ++j) A[j] = cvt_pk(p[2 * j], p[2 * j + 1]);
            pl32swap(A[0], A[2]); pl32swap(A[1], A[3]);
            pl32swap(A[4], A[6]); pl32swap(A[5], A[7]);
            u32x4 f0v; f0v[0] = A[0]; f0v[1] = A[1]; f0v[2] = A[2]; f0v[3] = A[3];
            u32x4 f1v; f1v[0] = A[4]; f1v[1] = A[5]; f1v[2] = A[6]; f1v[3] = A[7];
            bf16x8 frag[2] = { __builtin_bit_cast(bf16x8, f0v), __builtin_bit_cast(bf16x8, f1v) };

            __builtin_amdgcn_s_setprio(1);
#pragma unroll
            for (int ksl = 0; ksl < 2; ++ksl) {
                const int ksg = kb * 2 + ksl;
                bf16x8 vf0 = *(const bf16x8*)(Vbase + swz(la31, ksg * 16 + hi * 8));
                bf16x8 vf1 = *(const bf16x8*)(Vbase + swz(32 + la31, ksg * 16 + hi * 8));
                oacc[0] = MFMA32(vf0, frag[ksl], oacc[0]);
                oacc[1] = MFMA32(vf1, frag[ksl], oacc[1]);
            }
            __builtin_amdgcn_s_setprio(0);
        }
    }

    // ---- epilogue: combine l across lane pair (shfl), divide, store ----
    {
        float l_tot = l_run + __shfl_xor(l_run, 32);
        float inv = __builtin_amdgcn_rcpf(l_tot);
        float* obase = Og + ((size_t)q * NH + head) * DIM;
#pragma unroll
        for (int nt = 0; nt < 2; ++nt)
#pragma unroll
            for (int rq = 0; rq < 4; ++rq) {
                float4 o;
                o.x = oacc[nt][rq * 4 + 0] * inv;
                o.y = oacc[nt][rq * 4 + 1] * inv;
                o.z = oacc[nt][rq * 4 + 2] * inv;
                o.w = oacc[nt][rq * 4 + 3] * inv;
                *(float4*)(obase + nt * 32 + rq * 8 + hi * 4) = o;
            }
    }
}

extern "C" void kernel_launch(void* const* d_in, const int* in_sizes, int n_in,
                              void* d_out, int out_size, void* d_ws, size_t ws_size,
                              hipStream_t stream) {
    const float* q = (const float*)d_in[0];
    const float* k = (const float*)d_in[1];
    const float* v = (const float*)d_in[2];
    float* out = (float*)d_out;
    dim3 grid(512), block(256);
    hipLaunchKernelGGL(fa_kernel, grid, block, 0, stream, q, k, v, out);
}

// Round 5
// 204.012 us; speedup vs baseline: 2.7643x; 1.1699x over previous
//
#include <hip/hip_runtime.h>
#include <hip/hip_bf16.h>

typedef __attribute__((ext_vector_type(8))) short bf16x8;
typedef __attribute__((ext_vector_type(8))) unsigned short u16x8;
typedef __attribute__((ext_vector_type(16))) float f32x16;
typedef __attribute__((ext_vector_type(4))) unsigned int u32x4;

#define MFMA32(a, b, c) __builtin_amdgcn_mfma_f32_32x32x16_bf16(a, b, c, 0, 0, 0)

constexpr int NSEQ = 8192;
constexpr int NH   = 8;
constexpr int DIM  = 64;
constexpr int KVB  = 64;
constexpr int QB   = 128;   // 4 waves x 32 q-rows
constexpr int NT   = NSEQ / KVB;         // 128 tiles
constexpr int SLAB = KVB * DIM;          // 4096 ushorts = 8KB per tile slab
constexpr float SCL2 = 0.18033688011112042f;  // 0.125 * log2(e)

__device__ __forceinline__ unsigned cvt_pk(float lo, float hi) {
    unsigned r;
    asm("v_cvt_pk_bf16_f32 %0, %1, %2" : "=v"(r) : "v"(lo), "v"(hi));
    return r;
}
__device__ __forceinline__ float exp2f_fast(float x) {
    float r;
    asm("v_exp_f32 %0, %1" : "=v"(r) : "v"(x));
    return r;
}
// safe ONLY with provably-distinct operands (distinct live values)
__device__ __forceinline__ void pl32swap(unsigned& a, unsigned& b) {
    asm("v_permlane32_swap_b32 %0, %1" : "+v"(a), "+v"(b));
}
// XOR-swizzled LDS index (ushort units) for [row][64] bf16 tiles, 16B chunks
__device__ __forceinline__ int swz(int row, int col) {
    return row * 64 + ((((col >> 3) ^ row) & 7) << 3) + (col & 7);
}

// ============ prep: fp32 K/V -> bf16 swizzled tile slabs in workspace ============
// K slab (h,t): byte b: row r=b/128, slot s=(b/16)%8, holds chunk c=s^(r&7):
//   K[t*64+r][h][c*8 + (b%16)/2]
// V slab (h,t): row d=b/128, slot s, chunk c=s^(d&7): V[t*64 + c*8 + (b%16)/2][h][d]
__global__ __launch_bounds__(256, 4)
void prep_kernel(const float* __restrict__ Kg, const float* __restrict__ Vg,
                 unsigned short* __restrict__ Kws, unsigned short* __restrict__ Vws) {
    __shared__ float Vf[64][65];
    const int tid = threadIdx.x;
    const int bid = blockIdx.x;
    if (bid < 1024) {  // ---- K: direct swizzled convert ----
        const int h = bid >> 7, t = bid & 127;
        unsigned short* dst = Kws + (size_t)bid * SLAB;
#pragma unroll
        for (int j = 0; j < 2; ++j) {
            const int m = tid * 2 + j;
            const int r = m >> 3, s = m & 7, c = s ^ (r & 7);
            const float* src = Kg + ((size_t)(t * 64 + r) * NH + h) * DIM + c * 8;
            float4 a = ((const float4*)src)[0];
            float4 b = ((const float4*)src)[1];
            u32x4 w;
            w[0] = cvt_pk(a.x, a.y); w[1] = cvt_pk(a.z, a.w);
            w[2] = cvt_pk(b.x, b.y); w[3] = cvt_pk(b.z, b.w);
            *(u32x4*)(dst + m * 8) = w;
        }
    } else {           // ---- V: transpose via LDS, then swizzled convert ----
        const int hb = bid - 1024;
        const int h = hb >> 7, t = hb & 127;
        const int key = tid >> 2, dc = (tid & 3) * 16;
        const float* src = Vg + ((size_t)(t * 64 + key) * NH + h) * DIM + dc;
#pragma unroll
        for (int i = 0; i < 4; ++i) {
            float4 a = ((const float4*)src)[i];
            Vf[key][dc + i * 4 + 0] = a.x; Vf[key][dc + i * 4 + 1] = a.y;
            Vf[key][dc + i * 4 + 2] = a.z; Vf[key][dc + i * 4 + 3] = a.w;
        }
        __syncthreads();
        unsigned short* dst = Vws + (size_t)hb * SLAB;
#pragma unroll
        for (int j = 0; j < 2; ++j) {
            const int m = tid * 2 + j;
            const int d = m >> 3, s = m & 7, c = s ^ (d & 7);
            u32x4 w;
            w[0] = cvt_pk(Vf[c * 8 + 0][d], Vf[c * 8 + 1][d]);
            w[1] = cvt_pk(Vf[c * 8 + 2][d], Vf[c * 8 + 3][d]);
            w[2] = cvt_pk(Vf[c * 8 + 4][d], Vf[c * 8 + 5][d]);
            w[3] = cvt_pk(Vf[c * 8 + 6][d], Vf[c * 8 + 7][d]);
            *(u32x4*)(dst + m * 8) = w;
        }
    }
}

// ============ main attention kernel: bf16 slabs -> LDS (dbuf) ============
__global__ __launch_bounds__(256, 2)
void fa_kernel(const float* __restrict__ Qg, const unsigned short* __restrict__ Kws,
               const unsigned short* __restrict__ Vws, float* __restrict__ Og) {
    __shared__ unsigned short Kb[2][SLAB];
    __shared__ unsigned short Vb[2][SLAB];

    const int tid  = threadIdx.x;
    const int lane = tid & 63;
    const int wave = tid >> 6;
    const int la31 = lane & 31;
    const int hi   = lane >> 5;
    const int head  = blockIdx.x & 7;    // head pinned per XCD
    const int qtile = blockIdx.x >> 3;
    const int q     = qtile * QB + wave * 32 + la31;

    // ---- persistent Q B-fragments: qf[kd] = Q[q][16kd + 8hi + 0..7] * SCL2 ----
    bf16x8 qf[4];
#pragma unroll
    for (int kd = 0; kd < 4; ++kd) {
        const float* qp = Qg + ((size_t)q * NH + head) * DIM + kd * 16 + hi * 8;
        float4 a = ((const float4*)qp)[0];
        float4 b = ((const float4*)qp)[1];
        u32x4 w;
        w[0] = cvt_pk(a.x * SCL2, a.y * SCL2);
        w[1] = cvt_pk(a.z * SCL2, a.w * SCL2);
        w[2] = cvt_pk(b.x * SCL2, b.y * SCL2);
        w[3] = cvt_pk(b.z * SCL2, b.w * SCL2);
        qf[kd] = __builtin_bit_cast(bf16x8, w);
    }

    // ---- staging: thread owns 32B of K slab + 32B of V slab, linear ----
    const unsigned short* ksl = Kws + (size_t)head * NT * SLAB + tid * 16;
    const unsigned short* vsl = Vws + (size_t)head * NT * SLAB + tid * 16;

    f32x16 oacc[2];
#pragma unroll
    for (int nt = 0; nt < 2; ++nt)
#pragma unroll
        for (int i = 0; i < 16; ++i) oacc[nt][i] = 0.f;
    float m_run = -1e30f, l_run = 0.f;

    // prologue: load tile 0 into regs
    u16x8 kr0 = *(const u16x8*)ksl, kr1 = *(const u16x8*)(ksl + 8);
    u16x8 vr0 = *(const u16x8*)vsl, vr1 = *(const u16x8*)(vsl + 8);
    ksl += SLAB; vsl += SLAB;

    for (int t = 0; t < NT; ++t) {
        const int cur = t & 1;
        // ---- stage regs -> LDS (linear b128, swizzle baked into slab) ----
        *(u16x8*)&Kb[cur][tid * 16]     = kr0;
        *(u16x8*)&Kb[cur][tid * 16 + 8] = kr1;
        *(u16x8*)&Vb[cur][tid * 16]     = vr0;
        *(u16x8*)&Vb[cur][tid * 16 + 8] = vr1;
        __syncthreads();
        // ---- issue next tile's loads; latency hides under compute ----
        if (t + 1 < NT) {
            kr0 = *(const u16x8*)ksl; kr1 = *(const u16x8*)(ksl + 8);
            vr0 = *(const u16x8*)vsl; vr1 = *(const u16x8*)(vsl + 8);
            ksl += SLAB; vsl += SLAB;
        }
        const unsigned short* Kbase = &Kb[cur][0];
        const unsigned short* Vbase = &Vb[cur][0];

        // ---- S^T = K (Q*scale)^T : 8 MFMA 32x32x16 ----
        f32x16 s0, s1;
#pragma unroll
        for (int i = 0; i < 16; ++i) { s0[i] = 0.f; s1[i] = 0.f; }
        __builtin_amdgcn_s_setprio(1);
#pragma unroll
        for (int kd = 0; kd < 4; ++kd) {
            bf16x8 k0 = *(const bf16x8*)(Kbase + swz(la31, kd * 16 + hi * 8));
            bf16x8 k1 = *(const bf16x8*)(Kbase + swz(32 + la31, kd * 16 + hi * 8));
            s0 = MFMA32(k0, qf[kd], s0);
            s1 = MFMA32(k1, qf[kd], s1);
        }
        __builtin_amdgcn_s_setprio(0);

        // ---- lane-local max over 32 scores, then pair-combine via shfl ----
        float pmv[16];
#pragma unroll
        for (int i = 0; i < 16; ++i) pmv[i] = fmaxf(s0[i], s1[i]);
#pragma unroll
        for (int st = 8; st >= 1; st >>= 1)
#pragma unroll
            for (int i = 0; i < 8; ++i)
                if (i < st) pmv[i] = fmaxf(pmv[i], pmv[i + st]);
        float pm = pmv[0];
        pm = fmaxf(pm, __shfl_xor(pm, 32));  // pair lanes share a q-row

        // ---- defer-max (T13, THR=8 in log2 domain) ----
        if (__any(pm > m_run + 8.f)) {
            float mnew = fmaxf(m_run, pm);
            float corr = exp2f_fast(m_run - mnew);
            m_run = mnew;
            l_run *= corr;
#pragma unroll
            for (int i = 0; i < 16; ++i) { oacc[0][i] *= corr; oacc[1][i] *= corr; }
        }

        // ---- per key-block: exp, pack P in-register (T12), PV MFMAs ----
#pragma unroll
        for (int kb = 0; kb < 2; ++kb) {
            const f32x16& s = kb ? s1 : s0;
            float p[16];
#pragma unroll
            for (int i = 0; i < 16; ++i) p[i] = exp2f_fast(s[i] - m_run);
            float ts[8];
#pragma unroll
            for (int i = 0; i < 8; ++i) ts[i] = p[i] + p[i + 8];
#pragma unroll
            for (int i = 0; i < 4; ++i) ts[i] += ts[i + 4];
            l_run += (ts[0] + ts[1]) + (ts[2] + ts[3]);
            unsigned A[8];
#pragma unroll
            for (int j = 0; j < 8; ++j) A[j] = cvt_pk(p[2 * j], p[2 * j + 1]);
            pl32swap(A[0], A[2]); pl32swap(A[1], A[3]);
            pl32swap(A[4], A[6]); pl32swap(A[5], A[7]);
            u32x4 f0v; f0v[0] = A[0]; f0v[1] = A[1]; f0v[2] = A[2]; f0v[3] = A[3];
            u32x4 f1v; f1v[0] = A[4]; f1v[1] = A[5]; f1v[2] = A[6]; f1v[3] = A[7];
            bf16x8 frag[2] = { __builtin_bit_cast(bf16x8, f0v), __builtin_bit_cast(bf16x8, f1v) };

            __builtin_amdgcn_s_setprio(1);
#pragma unroll
            for (int ksl2 = 0; ksl2 < 2; ++ksl2) {
                const int ksg = kb * 2 + ksl2;
                bf16x8 vf0 = *(const bf16x8*)(Vbase + swz(la31, ksg * 16 + hi * 8));
                bf16x8 vf1 = *(const bf16x8*)(Vbase + swz(32 + la31, ksg * 16 + hi * 8));
                oacc[0] = MFMA32(vf0, frag[ksl2], oacc[0]);
                oacc[1] = MFMA32(vf1, frag[ksl2], oacc[1]);
            }
            __builtin_amdgcn_s_setprio(0);
        }
    }

    // ---- epilogue ----
    {
        float l_tot = l_run + __shfl_xor(l_run, 32);
        float inv = __builtin_amdgcn_rcpf(l_tot);
        float* obase = Og + ((size_t)q * NH + head) * DIM;
#pragma unroll
        for (int nt = 0; nt < 2; ++nt)
#pragma unroll
            for (int rq = 0; rq < 4; ++rq) {
                float4 o;
                o.x = oacc[nt][rq * 4 + 0] * inv;
                o.y = oacc[nt][rq * 4 + 1] * inv;
                o.z = oacc[nt][rq * 4 + 2] * inv;
                o.w = oacc[nt][rq * 4 + 3] * inv;
                *(float4*)(obase + nt * 32 + rq * 8 + hi * 4) = o;
            }
    }
}

// ============ fallback (round-4 proven kernel) if ws too small ============
__global__ __launch_bounds__(256, 2)
void fb_kernel(const float* __restrict__ Qg, const float* __restrict__ Kg,
               const float* __restrict__ Vg, float* __restrict__ Og) {
    __shared__ unsigned short Kl[KVB][DIM];
    __shared__ unsigned short Vt[DIM][KVB];
    unsigned short* Kbase = &Kl[0][0];
    unsigned short* Vbase = &Vt[0][0];
    const int tid  = threadIdx.x;
    const int lane = tid & 63;
    const int wave = tid >> 6;
    const int la31 = lane & 31;
    const int hi   = lane >> 5;
    const int head  = blockIdx.x & 7;
    const int qtile = blockIdx.x >> 3;
    const int q     = qtile * QB + wave * 32 + la31;
    bf16x8 qf[4];
#pragma unroll
    for (int kd = 0; kd < 4; ++kd) {
        const float* qp = Qg + ((size_t)q * NH + head) * DIM + kd * 16 + hi * 8;
        float4 a = ((const float4*)qp)[0];
        float4 b = ((const float4*)qp)[1];
        u32x4 w;
        w[0] = cvt_pk(a.x * SCL2, a.y * SCL2);
        w[1] = cvt_pk(a.z * SCL2, a.w * SCL2);
        w[2] = cvt_pk(b.x * SCL2, b.y * SCL2);
        w[3] = cvt_pk(b.z * SCL2, b.w * SCL2);
        qf[kd] = __builtin_bit_cast(bf16x8, w);
    }
    const int ksrow = tid & 63;
    const int kscol = (tid >> 6) * 16;
    const int vpair = tid & 31;
    const int vcg   = tid >> 5;
    const float* kptr  = Kg + ((size_t)ksrow * NH + head) * DIM + kscol;
    const float* vptr0 = Vg + ((size_t)(2 * vpair) * NH + head) * DIM + vcg * 8;
    const float* vptr1 = vptr0 + NH * DIM;
    constexpr size_t STRIDE = (size_t)KVB * NH * DIM;
    const int kIdx0 = swz(ksrow, kscol);
    const int kIdx1 = swz(ksrow, kscol + 8);
    f32x16 oacc[2];
#pragma unroll
    for (int nt = 0; nt < 2; ++nt)
#pragma unroll
        for (int i = 0; i < 16; ++i) oacc[nt][i] = 0.f;
    float m_run = -1e30f, l_run = 0.f;
    float4 kr0 = ((const float4*)kptr)[0], kr1 = ((const float4*)kptr)[1];
    float4 kr2 = ((const float4*)kptr)[2], kr3 = ((const float4*)kptr)[3];
    float4 va0 = ((const float4*)vptr0)[0], va1 = ((const float4*)vptr0)[1];
    float4 vb0 = ((const float4*)vptr1)[0], vb1 = ((const float4*)vptr1)[1];
    kptr += STRIDE; vptr0 += STRIDE; vptr1 += STRIDE;
    for (int t = 0; t < NT; ++t) {
        __syncthreads();
        {
            u32x4 w;
            w[0] = cvt_pk(kr0.x, kr0.y); w[1] = cvt_pk(kr0.z, kr0.w);
            w[2] = cvt_pk(kr1.x, kr1.y); w[3] = cvt_pk(kr1.z, kr1.w);
            *(u32x4*)(Kbase + kIdx0) = w;
            w[0] = cvt_pk(kr2.x, kr2.y); w[1] = cvt_pk(kr2.z, kr2.w);
            w[2] = cvt_pk(kr3.x, kr3.y); w[3] = cvt_pk(kr3.z, kr3.w);
            *(u32x4*)(Kbase + kIdx1) = w;
        }
        {
            *(unsigned*)(Vbase + swz(vcg * 8 + 0, 2 * vpair)) = cvt_pk(va0.x, vb0.x);
            *(unsigned*)(Vbase + swz(vcg * 8 + 1, 2 * vpair)) = cvt_pk(va0.y, vb0.y);
            *(unsigned*)(Vbase + swz(vcg * 8 + 2, 2 * vpair)) = cvt_pk(va0.z, vb0.z);
            *(unsigned*)(Vbase + swz(vcg * 8 + 3, 2 * vpair)) = cvt_pk(va0.w, vb0.w);
            *(unsigned*)(Vbase + swz(vcg * 8 + 4, 2 * vpair)) = cvt_pk(va1.x, vb1.x);
            *(unsigned*)(Vbase + swz(vcg * 8 + 5, 2 * vpair)) = cvt_pk(va1.y, vb1.y);
            *(unsigned*)(Vbase + swz(vcg * 8 + 6, 2 * vpair)) = cvt_pk(va1.z, vb1.z);
            *(unsigned*)(Vbase + swz(vcg * 8 + 7, 2 * vpair)) = cvt_pk(va1.w, vb1.w);
        }
        __syncthreads();
        if (t + 1 < NT) {
            kr0 = ((const float4*)kptr)[0]; kr1 = ((const float4*)kptr)[1];
            kr2 = ((const float4*)kptr)[2]; kr3 = ((const float4*)kptr)[3];
            va0 = ((const float4*)vptr0)[0]; va1 = ((const float4*)vptr0)[1];
            vb0 = ((const float4*)vptr1)[0]; vb1 = ((const float4*)vptr1)[1];
            kptr += STRIDE; vptr0 += STRIDE; vptr1 += STRIDE;
        }
        f32x16 s0, s1;
#pragma unroll
        for (int i = 0; i < 16; ++i) { s0[i] = 0.f; s1[i] = 0.f; }
        __builtin_amdgcn_s_setprio(1);
#pragma unroll
        for (int kd = 0; kd < 4; ++kd) {
            bf16x8 k0 = *(const bf16x8*)(Kbase + swz(la31, kd * 16 + hi * 8));
            bf16x8 k1 = *(const bf16x8*)(Kbase + swz(32 + la31, kd * 16 + hi * 8));
            s0 = MFMA32(k0, qf[kd], s0);
            s1 = MFMA32(k1, qf[kd], s1);
        }
        __builtin_amdgcn_s_setprio(0);
        float pmv[16];
#pragma unroll
        for (int i = 0; i < 16; ++i) pmv[i] = fmaxf(s0[i], s1[i]);
#pragma unroll
        for (int st = 8; st >= 1; st >>= 1)
#pragma unroll
            for (int i = 0; i < 8; ++i)
                if (i < st) pmv[i] = fmaxf(pmv[i], pmv[i + st]);
        float pm = pmv[0];
        pm = fmaxf(pm, __shfl_xor(pm, 32));
        if (__any(pm > m_run + 8.f)) {
            float mnew = fmaxf(m_run, pm);
            float corr = exp2f_fast(m_run - mnew);
            m_run = mnew;
            l_run *= corr;
#pragma unroll
            for (int i = 0; i < 16; ++i) { oacc[0][i] *= corr; oacc[1][i] *= corr; }
        }
#pragma unroll
        for (int kb = 0; kb < 2; ++kb) {
            const f32x16& s = kb ? s1 : s0;
            float p[16];
#pragma unroll
            for (int i = 0; i < 16; ++i) p[i] = exp2f_fast(s[i] - m_run);
            float ts[8];
#pragma unroll
            for (int i = 0; i < 8; ++i) ts[i] = p[i] + p[i + 8];
#pragma unroll
            for (int i = 0; i < 4; ++i) ts[i] += ts[i + 4];
            l_run += (ts[0] + ts[1]) + (ts[2] + ts[3]);
            unsigned A[8];
#pragma unroll
            for (int j = 0; j < 8; ++j) A[j] = cvt_pk(p[2 * j], p[2 * j + 1]);
            pl32swap(A[0], A[2]); pl32swap(A[1], A[3]);
            pl32swap(A[4], A[6]); pl32swap(A[5], A[7]);
            u32x4 f0v; f0v[0] = A[0]; f0v[1] = A[1]; f0v[2] = A[2]; f0v[3] = A[3];
            u32x4 f1v; f1v[0] = A[4]; f1v[1] = A[5]; f1v[2] = A[6]; f1v[3] = A[7];
            bf16x8 frag[2] = { __builtin_bit_cast(bf16x8, f0v), __builtin_bit_cast(bf16x8, f1v) };
            __builtin_amdgcn_s_setprio(1);
#pragma unroll
            for (int ksl = 0; ksl < 2; ++ksl) {
                const int ksg = kb * 2 + ksl;
                bf16x8 vf0 = *(const bf16x8*)(Vbase + swz(la31, ksg * 16 + hi * 8));
                bf16x8 vf1 = *(const bf16x8*)(Vbase + swz(32 + la31, ksg * 16 + hi * 8));
                oacc[0] = MFMA32(vf0, frag[ksl], oacc[0]);
                oacc[1] = MFMA32(vf1, frag[ksl], oacc[1]);
            }
            __builtin_amdgcn_s_setprio(0);
        }
    }
    {
        float l_tot = l_run + __shfl_xor(l_run, 32);
        float inv = __builtin_amdgcn_rcpf(l_tot);
        float* obase = Og + ((size_t)q * NH + head) * DIM;
#pragma unroll
        for (int nt = 0; nt < 2; ++nt)
#pragma unroll
            for (int rq = 0; rq < 4; ++rq) {
                float4 o;
                o.x = oacc[nt][rq * 4 + 0] * inv;
                o.y = oacc[nt][rq * 4 + 1] * inv;
                o.z = oacc[nt][rq * 4 + 2] * inv;
                o.w = oacc[nt][rq * 4 + 3] * inv;
                *(float4*)(obase + nt * 32 + rq * 8 + hi * 4) = o;
            }
    }
}

extern "C" void kernel_launch(void* const* d_in, const int* in_sizes, int n_in,
                              void* d_out, int out_size, void* d_ws, size_t ws_size,
                              hipStream_t stream) {
    const float* q = (const float*)d_in[0];
    const float* k = (const float*)d_in[1];
    const float* v = (const float*)d_in[2];
    float* out = (float*)d_out;
    constexpr size_t KV_WS = 2ull * NH * NT * SLAB * sizeof(unsigned short);  // 16.78 MB
    if (ws_size >= KV_WS) {
        unsigned short* Kws = (unsigned short*)d_ws;
        unsigned short* Vws = Kws + (size_t)NH * NT * SLAB;
        hipLaunchKernelGGL(prep_kernel, dim3(2048), dim3(256), 0, stream, k, v, Kws, Vws);
        hipLaunchKernelGGL(fa_kernel, dim3(512), dim3(256), 0, stream, q, Kws, Vws, out);
    } else {
        hipLaunchKernelGGL(fb_kernel, dim3(512), dim3(256), 0, stream, q, k, v, out);
    }
}